// Round 15
// baseline (525.608 us; speedup 1.0000x reference)
//
#include <hip/hip_runtime.h>
#include <hip/hip_bf16.h>

// Problem constants
constexpr int N_  = 50000;
constexpr int E_  = 800000;
constexpr int E2_ = 850000;   // E + N self loops
constexpr int FIN = 128;
constexpr int FH  = 256;      // H * C = 4 * 64
constexpr float BN_EPS = 1e-5f;
constexpr float NEG_ATT = 0.2f;
constexpr float NEG_OUT = 0.1f;
constexpr size_t OUT0 = (size_t)N_ * FH;   // 12.8M feature elems (fp32)
constexpr size_t OUT1 = (size_t)2 * E_;    // 1.6M edge elems (fp32)
constexpr int SCAN_NBLK = (N_ + 255) / 256;   // 196
constexpr int ATTR_NBLK = 1024;

static inline int cdiv(int a, int b){ return (a + b - 1) / b; }

using short8 = __attribute__((ext_vector_type(8))) short;
using f32x4  = __attribute__((ext_vector_type(4))) float;
using f32x2  = __attribute__((ext_vector_type(2))) float;

#if __has_builtin(__builtin_amdgcn_cvt_pk_f32_fp8) && __has_builtin(__builtin_amdgcn_cvt_pk_fp8_f32)
#define FP8_HW 1
#else
#define FP8_HW 0
#endif

__device__ inline float lrelu(float v, float ns){ return v > 0.f ? v : ns * v; }

__device__ inline unsigned short bf16rne(float f){
    unsigned u = __float_as_uint(f);
    u += 0x7fffu + ((u >> 16) & 1u);
    return (unsigned short)(u >> 16);
}
__device__ inline float bf16lo(unsigned u){ return __uint_as_float(u << 16); }
__device__ inline float bf16hi(unsigned u){ return __uint_as_float(u & 0xffff0000u); }
__device__ inline float bf16f(unsigned short v){ return __uint_as_float((unsigned)v << 16); }

// ---- software e4m3fn codec (fallback only; HW cvt used when available) ----
__device__ inline float fp8dec1(unsigned b){
    unsigned s = b >> 7;
    unsigned e = (b >> 3) & 15;
    unsigned m = b & 7;
    float v;
    if (e == 0) v = (float)m * 0.001953125f;           // m * 2^-9
    else        v = __uint_as_float(((e + 120u) << 23) | (m << 20));
    return s ? -v : v;
}
__device__ inline unsigned fp8enc1(float f){
    unsigned u = __float_as_uint(f);
    unsigned s = (u >> 31) << 7;
    float af = fabsf(f);
    if (af >= 448.f) return s | 0x7Eu;
    if (af < 0.0009765625f) return s;                   // < 2^-10 -> 0
    if (af < 0.015625f){                                // subnormal range
        int q = (int)(af * 512.f + 0.5f);               // round to m*2^-9
        return s | (unsigned)q;
    }
    unsigned a = u & 0x7fffffffu;
    a += 0x7FFFFu + ((a >> 20) & 1u);                   // RNE at mantissa bit 20
    int e8 = (int)(a >> 23) - 120;
    unsigned m8 = (a >> 20) & 7u;
    if (e8 > 15 || (e8 == 15 && m8 == 7u)) return s | 0x7Eu;
    return s | ((unsigned)e8 << 3) | m8;
}
__device__ inline void dec4(unsigned g, float& f0, float& f1, float& f2, float& f3){
#if FP8_HW
    f32x2 lo = __builtin_amdgcn_cvt_pk_f32_fp8((int)g, false);
    f32x2 hi = __builtin_amdgcn_cvt_pk_f32_fp8((int)g, true);
    f0 = lo[0]; f1 = lo[1]; f2 = hi[0]; f3 = hi[1];
#else
    f0 = fp8dec1(g & 255u); f1 = fp8dec1((g >> 8) & 255u);
    f2 = fp8dec1((g >> 16) & 255u); f3 = fp8dec1(g >> 24);
#endif
}
__device__ inline unsigned char fp8b(float f){
#if FP8_HW
    return (unsigned char)(__builtin_amdgcn_cvt_pk_fp8_f32(f, f, 0, false) & 0xff);
#else
    return (unsigned char)fp8enc1(f);
#endif
}

__global__ void k_sentinel(float* out, float v){ out[0] = v; }

__global__ void k_zero32(unsigned* p, int n){
    int i = blockIdx.x * blockDim.x + threadIdx.x;
    if (i < n) p[i] = 0u;
}

// ---------- W [K][256] fp32 -> WT [256][K] bf16 ----------
__global__ void k_w2t(const float* __restrict__ W, unsigned short* __restrict__ WT, int K){
    int i = blockIdx.x * blockDim.x + threadIdx.x;
    if (i >= K * 256) return;
    int k = i >> 8, c = i & 255;
    WT[(size_t)c * K + k] = bf16rne(W[i]);
}

// ---------- BatchNorm stats (fp32 input) ----------
__global__ void k_bn_stats(const float* __restrict__ x, int F,
                           float* __restrict__ sum, float* __restrict__ sumsq){
    int gid = blockIdx.x * blockDim.x + threadIdx.x;
    int T = gridDim.x * blockDim.x;      // 65536
    int c = gid % F;
    int r0 = gid / F;
    int rstep = T / F;
    float s = 0.f, s2 = 0.f;
    for (int r = r0; r < N_; r += rstep){
        float v = x[(size_t)r * F + c];
        s += v; s2 += v * v;
    }
    atomicAdd(&sum[c], s);
    atomicAdd(&sumsq[c], s2);
}

// ---------- BatchNorm stats (bf16 input) ----------
__global__ void k_bn_stats_b16(const unsigned short* __restrict__ x, int F,
                               float* __restrict__ sum, float* __restrict__ sumsq){
    int gid = blockIdx.x * blockDim.x + threadIdx.x;
    int T = gridDim.x * blockDim.x;
    int c = gid % F;
    int r0 = gid / F;
    int rstep = T / F;
    float s = 0.f, s2 = 0.f;
    for (int r = r0; r < N_; r += rstep){
        float v = bf16f(x[(size_t)r * F + c]);
        s += v; s2 += v * v;
    }
    atomicAdd(&sum[c], s);
    atomicAdd(&sumsq[c], s2);
}

// BN + lrelu, fp32 in -> bf16 out
__global__ void k_bn_apply_bf(const float* __restrict__ x, const float* __restrict__ sum,
                              const float* __restrict__ sumsq, const float* __restrict__ gamma,
                              const float* __restrict__ beta, unsigned short* __restrict__ out, int F){
    size_t tot = (size_t)N_ * F;
    size_t step = (size_t)gridDim.x * blockDim.x;
    for (size_t i = blockIdx.x * (size_t)blockDim.x + threadIdx.x; i < tot; i += step){
        int c = (int)(i % F);
        float mean = sum[c] / (float)N_;
        float var = sumsq[c] / (float)N_ - mean * mean;
        float v = (x[i] - mean) * rsqrtf(var + BN_EPS) * gamma[c] + beta[c];
        out[i] = bf16rne(lrelu(v, NEG_OUT));
    }
}

// BN + lrelu, bf16 in -> bf16 out
__global__ void k_bn_apply_b16(const unsigned short* __restrict__ x, const float* __restrict__ sum,
                               const float* __restrict__ sumsq, const float* __restrict__ gamma,
                               const float* __restrict__ beta, unsigned short* __restrict__ out, int F){
    size_t tot = (size_t)N_ * F;
    size_t step = (size_t)gridDim.x * blockDim.x;
    for (size_t i = blockIdx.x * (size_t)blockDim.x + threadIdx.x; i < tot; i += step){
        int c = (int)(i % F);
        float mean = sum[c] / (float)N_;
        float var = sumsq[c] / (float)N_ - mean * mean;
        float v = (bf16f(x[i]) - mean) * rsqrtf(var + BN_EPS) * gamma[c] + beta[c];
        out[i] = bf16rne(lrelu(v, NEG_OUT));
    }
}

// ---------- MFMA GEMM: C[M x 256] = A[M x K] @ B[K x 256]; writes bf16 + fp8 copies ----------
__global__ __launch_bounds__(256) void k_gemm_mfma(const unsigned short* __restrict__ A,
                                                   const unsigned short* __restrict__ WT,
                                                   unsigned short* __restrict__ C,
                                                   unsigned char* __restrict__ C8, int M, int K){
    __shared__ unsigned short Al[64][32];   // 4KB
    __shared__ unsigned short Bl[64][32];   // 4KB  (Bl[col][k])
    int tid = threadIdx.x;
    int w = tid >> 6;
    int l = tid & 63;
    int row0 = blockIdx.x * 64;
    int col0 = blockIdx.y * 64;
    f32x4 acc[4];
    #pragma unroll
    for (int m = 0; m < 4; ++m) acc[m] = (f32x4){0.f, 0.f, 0.f, 0.f};

    int srow = tid >> 2;
    int skq  = (tid & 3) * 8;

    for (int k0 = 0; k0 < K; k0 += 32){
        {
            short8 v = {0,0,0,0,0,0,0,0};
            if (row0 + srow < M)
                v = *reinterpret_cast<const short8*>(A + (size_t)(row0 + srow) * K + k0 + skq);
            *reinterpret_cast<short8*>(&Al[srow][skq]) = v;
        }
        {
            short8 v = *reinterpret_cast<const short8*>(WT + (size_t)(col0 + srow) * K + k0 + skq);
            *reinterpret_cast<short8*>(&Bl[srow][skq]) = v;
        }
        __syncthreads();
        short8 b = *reinterpret_cast<const short8*>(&Bl[w * 16 + (l & 15)][8 * (l >> 4)]);
        #pragma unroll
        for (int m = 0; m < 4; ++m){
            short8 a = *reinterpret_cast<const short8*>(&Al[m * 16 + (l & 15)][8 * (l >> 4)]);
            acc[m] = __builtin_amdgcn_mfma_f32_16x16x32_bf16(a, b, acc[m], 0, 0, 0);
        }
        __syncthreads();
    }
    int ccol = col0 + w * 16 + (l & 15);
    #pragma unroll
    for (int m = 0; m < 4; ++m){
        #pragma unroll
        for (int r = 0; r < 4; ++r){
            int row = row0 + m * 16 + (l >> 4) * 4 + r;
            if (row < M){
                float f = acc[m][r];
                C[(size_t)row * 256 + ccol]  = bf16rne(f);
                C8[(size_t)row * 256 + ccol] = fp8b(f);
            }
        }
    }
}

// ---------- per-node attention terms: one wave per node, bf16 h ----------
__global__ __launch_bounds__(256) void k_al(const unsigned short* __restrict__ hb,
                                            const float* __restrict__ asrc,
                                            const float* __restrict__ adst,
                                            float* __restrict__ als, float* __restrict__ ald){
    int n = blockIdx.x * 4 + (threadIdx.x >> 6);
    if (n >= N_) return;
    int lane = threadIdx.x & 63;
    uint2 g = *reinterpret_cast<const uint2*>(hb + (size_t)n * 256 + lane * 4);
    float h0 = bf16lo(g.x), h1 = bf16hi(g.x), h2 = bf16lo(g.y), h3 = bf16hi(g.y);
    float4 as = *reinterpret_cast<const float4*>(asrc + lane * 4);
    float4 ad = *reinterpret_cast<const float4*>(adst + lane * 4);
    float ps = h0*as.x + h1*as.y + h2*as.z + h3*as.w;
    float pd = h0*ad.x + h1*ad.y + h2*ad.z + h3*ad.w;
    #pragma unroll
    for (int m = 1; m < 16; m <<= 1){
        ps += __shfl_xor(ps, m, 64);
        pd += __shfl_xor(pd, m, 64);
    }
    if ((lane & 15) == 0){
        int hd = lane >> 4;
        als[(size_t)n*4 + hd] = ps;
        ald[(size_t)n*4 + hd] = pd;
    }
}

// ---------- edge_attr column sums: block partials (NO global atomics) ----------
__global__ __launch_bounds__(256) void k_attr_sum(const float* __restrict__ ea,
                                                  float* __restrict__ part){
    __shared__ float4 sdata[256];
    int tid = threadIdx.x;
    const float4* p = reinterpret_cast<const float4*>(ea);
    size_t step = (size_t)gridDim.x * 256;
    size_t end = (size_t)E_ * 4;
    size_t j = (size_t)blockIdx.x * 256 + tid;
    float4 a0 = make_float4(0.f,0.f,0.f,0.f), a1 = a0, a2 = a0, a3 = a0;
    for (; j + 3 * step < end; j += 4 * step){
        float4 v0 = p[j], v1 = p[j + step], v2 = p[j + 2*step], v3 = p[j + 3*step];
        a0.x += v0.x; a0.y += v0.y; a0.z += v0.z; a0.w += v0.w;
        a1.x += v1.x; a1.y += v1.y; a1.z += v1.z; a1.w += v1.w;
        a2.x += v2.x; a2.y += v2.y; a2.z += v2.z; a2.w += v2.w;
        a3.x += v3.x; a3.y += v3.y; a3.z += v3.z; a3.w += v3.w;
    }
    for (; j < end; j += step){
        float4 v = p[j];
        a0.x += v.x; a0.y += v.y; a0.z += v.z; a0.w += v.w;
    }
    a0.x += a1.x + a2.x + a3.x;  a0.y += a1.y + a2.y + a3.y;
    a0.z += a1.z + a2.z + a3.z;  a0.w += a1.w + a2.w + a3.w;
    sdata[tid] = a0;
    __syncthreads();
    #pragma unroll
    for (int s = 128; s >= 4; s >>= 1){
        if (tid < s){
            float4 o = sdata[tid + s];
            float4 m = sdata[tid];
            m.x += o.x; m.y += o.y; m.z += o.z; m.w += o.w;
            sdata[tid] = m;
        }
        __syncthreads();
    }
    if (tid < 4){
        float4 m = sdata[tid];
        float* pp = part + (size_t)blockIdx.x * 16 + tid * 4;
        pp[0] = m.x; pp[1] = m.y; pp[2] = m.z; pp[3] = m.w;
    }
}

// final reduce of part[ATTR_NBLK][16] -> asum[16]
__global__ __launch_bounds__(256) void k_attr_fin(const float* __restrict__ part,
                                                  float* __restrict__ asum){
    __shared__ float sd[256];
    int t = threadIdx.x;
    int col = t & 15, seg = t >> 4;   // 16 segments
    float s = 0.f;
    for (int b = seg; b < ATTR_NBLK; b += 16) s += part[(size_t)b * 16 + col];
    sd[t] = s;
    __syncthreads();
    #pragma unroll
    for (int off = 128; off >= 16; off >>= 1){
        if (t < off) sd[t] += sd[t + off];
        __syncthreads();
    }
    if (t < 16) asum[t] = sd[t];
}

// ---------- V[k][h]; alloop[h] ----------
__global__ void k_prep(const float* __restrict__ We, const float* __restrict__ aedge,
                       const float* __restrict__ asum, float* __restrict__ V,
                       float* __restrict__ alloop){
    __shared__ float Vs[64];
    int t = threadIdx.x;  // 64 threads
    int k = t >> 2, hd = t & 3;
    float s = 0.f;
    for (int c = 0; c < 64; ++c) s += We[k * 256 + hd * 64 + c] * aedge[hd * 64 + c];
    Vs[t] = s;
    V[t] = s;
    __syncthreads();
    if (t < 4){
        float r = 0.f;
        for (int kk = 0; kk < 16; ++kk) r += (asum[kk] / (float)E_) * Vs[kk * 4 + t];
        alloop[t] = r;
    }
}

// ---------- al_edge ----------
__global__ void k_al_edge(const float* __restrict__ ea, const float* __restrict__ V,
                          float* __restrict__ ale){
    int idx = blockIdx.x * blockDim.x + threadIdx.x;   // E*4
    if (idx >= E_ * 4) return;
    int e = idx >> 2, hd = idx & 3;
    const float* ep = ea + (size_t)e * 16;
    float s = 0.f;
    #pragma unroll
    for (int k = 0; k < 16; ++k) s += ep[k] * V[k * 4 + hd];
    ale[idx] = s;
}

// ---------- CSR build ----------
__global__ void k_count(const int* __restrict__ ei, int* __restrict__ counts){
    int e = blockIdx.x * blockDim.x + threadIdx.x;
    if (e >= E2_) return;
    int d = (e < E_) ? ei[E_ + e] : (e - E_);
    atomicAdd(&counts[d], 1);
}

__global__ __launch_bounds__(256) void k_scan_local(const int* __restrict__ counts,
                                                    int* __restrict__ rs,
                                                    int* __restrict__ bsum){
    __shared__ int sd[256];
    int t = threadIdx.x;
    int idx = blockIdx.x * 256 + t;
    int c = (idx < N_) ? counts[idx] : 0;
    sd[t] = c;
    __syncthreads();
    #pragma unroll
    for (int off = 1; off < 256; off <<= 1){
        int o = (t >= off) ? sd[t - off] : 0;
        __syncthreads();
        sd[t] += o;
        __syncthreads();
    }
    if (idx < N_) rs[idx] = sd[t] - c;
    if (t == 255) bsum[blockIdx.x] = sd[255];
}

__global__ __launch_bounds__(256) void k_scan_block(const int* __restrict__ bsum,
                                                    int* __restrict__ boff,
                                                    int* __restrict__ rs){
    __shared__ int sd[256];
    int t = threadIdx.x;
    int v = (t < SCAN_NBLK) ? bsum[t] : 0;
    sd[t] = v;
    __syncthreads();
    #pragma unroll
    for (int off = 1; off < 256; off <<= 1){
        int o = (t >= off) ? sd[t - off] : 0;
        __syncthreads();
        sd[t] += o;
        __syncthreads();
    }
    if (t < SCAN_NBLK) boff[t] = sd[t] - v;
    if (t == 0) rs[N_] = E2_;
}

__global__ __launch_bounds__(256) void k_scan_add(int* __restrict__ rs,
                                                  const int* __restrict__ boff){
    int idx = blockIdx.x * 256 + threadIdx.x;
    if (idx < N_) rs[idx] += boff[blockIdx.x];
}

// scatter packed (src, eid) in ONE 8B store
__global__ void k_scatter(const int* __restrict__ ei, const int* __restrict__ rs,
                          int* __restrict__ cursor, int2* __restrict__ sedge){
    int e = blockIdx.x * blockDim.x + threadIdx.x;
    if (e >= E2_) return;
    int s, d;
    if (e < E_){ s = ei[e]; d = ei[E_ + e]; }
    else { s = e - E_; d = s; }
    int slot = rs[d] + atomicAdd(&cursor[d], 1);
    sedge[slot] = make_int2(s, e);
}

// ---------- softmax stats: true segment max + denom per (node, head) ----------
__global__ __launch_bounds__(256) void k_smax(const int* __restrict__ rs,
        const int2* __restrict__ sedge, const float* __restrict__ als,
        const float* __restrict__ ald, const float* __restrict__ ale,
        const float* __restrict__ alloop, float2* __restrict__ mxden){
    int idx = blockIdx.x * 256 + threadIdx.x;   // N*4
    if (idx >= N_ * 4) return;
    int n = idx >> 2, hd = idx & 3;
    float aldn = ald[idx];
    float alp  = alloop[hd];
    int i0 = rs[n], i1 = rs[n + 1];
    float m = -3.0e38f, den = 0.f;
    for (int i = i0; i < i1; ++i){
        int2 se = sedge[i];
        float alE = (se.y < E_) ? ale[(size_t)se.y * 4 + hd] : alp;
        float lg = lrelu(als[(size_t)se.x * 4 + hd] + aldn + alE, NEG_ATT);
        float mn = fmaxf(m, lg);
        den = den * __expf(m - mn) + __expf(lg - mn);
        m = mn;
    }
    mxden[idx] = make_float2(m, 1.f / den);
}

// ---------- one wave per dst node, FOUR independent edge streams, fp8 gather ----------
// With precomputed (max, 1/den): p = exp(lg - max) is iteration-independent ->
// pure fma accumulation; streams merge with plain sums.
#define SUMM(OFF) { \
    a0+=__shfl_xor(a0,OFF,64); a1+=__shfl_xor(a1,OFF,64); a2+=__shfl_xor(a2,OFF,64); a3+=__shfl_xor(a3,OFF,64); \
    a4+=__shfl_xor(a4,OFF,64); a5+=__shfl_xor(a5,OFF,64); a6+=__shfl_xor(a6,OFF,64); a7+=__shfl_xor(a7,OFF,64); \
    a8+=__shfl_xor(a8,OFF,64); a9+=__shfl_xor(a9,OFF,64); aA+=__shfl_xor(aA,OFF,64); aB+=__shfl_xor(aB,OFF,64); \
    aC+=__shfl_xor(aC,OFF,64); aD+=__shfl_xor(aD,OFF,64); aE+=__shfl_xor(aE,OFF,64); aF+=__shfl_xor(aF,OFF,64); }

template<bool BF16OUT>
__global__ __launch_bounds__(256) void k_aggregate4(const unsigned char* __restrict__ hb8,
        const float* __restrict__ als, const float* __restrict__ ald,
        const float* __restrict__ ale, const float* __restrict__ alloop,
        const float2* __restrict__ mxden,
        const int* __restrict__ rs, const int2* __restrict__ sedge,
        const float* __restrict__ bias, void* __restrict__ outp){
    int n = blockIdx.x * 4 + (threadIdx.x >> 6);
    if (n >= N_) return;
    int lane = threadIdx.x & 63;
    int q  = lane >> 4;
    int sl = lane & 15;
    int col0 = sl * 16;
    int hd = sl >> 2;
    float aldn = ald[(size_t)n * 4 + hd];
    float alp  = alloop[hd];
    float2 md  = mxden[(size_t)n * 4 + hd];
    float mxn = md.x, invden = md.y;
    int i0 = rs[n], i1 = rs[n + 1];
    float a0=0.f,a1=0.f,a2=0.f,a3=0.f,a4=0.f,a5=0.f,a6=0.f,a7=0.f;
    float a8=0.f,a9=0.f,aA=0.f,aB=0.f,aC=0.f,aD=0.f,aE=0.f,aF=0.f;
    for (int i = i0 + q; i < i1; i += 4){
        int2 se = sedge[i];
        int s   = se.x;
        float alE = (se.y < E_) ? ale[(size_t)se.y * 4 + hd] : alp;
        float lg = lrelu(als[(size_t)s * 4 + hd] + aldn + alE, NEG_ATT);
        float p  = __expf(lg - mxn);
        uint4 g = *reinterpret_cast<const uint4*>(hb8 + (size_t)s * 256 + col0);
        float t0, t1, t2, t3;
        dec4(g.x, t0, t1, t2, t3);
        a0 += p*t0;  a1 += p*t1;  a2 += p*t2;  a3 += p*t3;
        dec4(g.y, t0, t1, t2, t3);
        a4 += p*t0;  a5 += p*t1;  a6 += p*t2;  a7 += p*t3;
        dec4(g.z, t0, t1, t2, t3);
        a8 += p*t0;  a9 += p*t1;  aA += p*t2;  aB += p*t3;
        dec4(g.w, t0, t1, t2, t3);
        aC += p*t0;  aD += p*t1;  aE += p*t2;  aF += p*t3;
    }
    SUMM(16)
    SUMM(32)
    float v0, v1, v2, v3;
    if      (q == 0){ v0 = a0; v1 = a1; v2 = a2; v3 = a3; }
    else if (q == 1){ v0 = a4; v1 = a5; v2 = a6; v3 = a7; }
    else if (q == 2){ v0 = a8; v1 = a9; v2 = aA; v3 = aB; }
    else            { v0 = aC; v1 = aD; v2 = aE; v3 = aF; }
    int wc = col0 + q * 4;
    float4 b4 = *reinterpret_cast<const float4*>(bias + wc);
    float r0 = lrelu(v0 * invden + b4.x, NEG_OUT);
    float r1 = lrelu(v1 * invden + b4.y, NEG_OUT);
    float r2 = lrelu(v2 * invden + b4.z, NEG_OUT);
    float r3 = lrelu(v3 * invden + b4.w, NEG_OUT);
    if (BF16OUT){
        ushort4 pk;
        pk.x = bf16rne(r0); pk.y = bf16rne(r1); pk.z = bf16rne(r2); pk.w = bf16rne(r3);
        *reinterpret_cast<ushort4*>((unsigned short*)outp + (size_t)n * 256 + wc) = pk;
    } else {
        *reinterpret_cast<float4*>((float*)outp + (size_t)n * 256 + wc) =
            make_float4(r0, r1, r2, r3);
    }
}

// ---------- edge_index passthrough (fp32, bit-exact) ----------
__global__ void k_edge_store(const int* __restrict__ ei, float* __restrict__ out){
    int j = blockIdx.x * blockDim.x + threadIdx.x;     // 2E
    if (j >= (int)OUT1) return;
    out[j] = (float)ei[j];
}

extern "C" void kernel_launch(void* const* d_in, const int* in_sizes, int n_in,
                              void* d_out, int out_size, void* d_ws, size_t ws_size,
                              hipStream_t stream){
    const float* x    = (const float*)d_in[0];
    const int*   ei   = (const int*)d_in[1];
    const float* ea   = (const float*)d_in[2];
    const float* bn1g = (const float*)d_in[3];
    const float* bn1b = (const float*)d_in[4];
    const float* W1   = (const float*)d_in[5];
    const float* We1  = (const float*)d_in[6];
    const float* as1  = (const float*)d_in[7];
    const float* ad1  = (const float*)d_in[8];
    const float* ae1  = (const float*)d_in[9];
    const float* b1   = (const float*)d_in[10];
    const float* bn2g = (const float*)d_in[11];
    const float* bn2b = (const float*)d_in[12];
    const float* W2   = (const float*)d_in[13];
    const float* We2  = (const float*)d_in[14];
    const float* as2  = (const float*)d_in[15];
    const float* ad2  = (const float*)d_in[16];
    const float* ae2  = (const float*)d_in[17];
    const float* b2   = (const float*)d_in[18];
    float* out = (float*)d_out;

    bool ok = (n_in >= 19)
           && (in_sizes[0] == N_ * FIN)
           && (in_sizes[1] == 2 * E_)
           && (in_sizes[2] == E_ * 16)
           && (out_size == (int)(OUT0 + OUT1));
    if (!ok){ k_sentinel<<<1,1,0,stream>>>(out, 7777.f); return; }

    char* w = (char*)d_ws;
    size_t off = 0;
    auto alloc = [&](size_t bytes) -> void* {
        off = (off + 255) & ~(size_t)255;
        void* p = w + off;
        off += bytes;
        return p;
    };
    float* stats  = (float*)alloc(512 * 4);
    float* asum   = (float*)alloc(16 * 4);
    float* apart  = (float*)alloc((size_t)ATTR_NBLK * 16 * 4);   // 64KB
    float* Vbuf   = (float*)alloc(64 * 4);
    float* alloop = (float*)alloc(4 * 4);
    float* als    = (float*)alloc((size_t)N_ * 4 * 4);
    float* ald    = (float*)alloc((size_t)N_ * 4 * 4);
    float2* mxden = (float2*)alloc((size_t)N_ * 4 * 8);          // 1.6MB
    float* ale    = (float*)alloc((size_t)E_ * 4 * 4);           // 12.8MB
    int*   rs     = (int*)alloc((size_t)(N_ + 1) * 4);
    int*   counts = (int*)alloc((size_t)N_ * 4);
    int*   cursor = (int*)alloc((size_t)N_ * 4);
    int*   bsum   = (int*)alloc((size_t)SCAN_NBLK * 4);
    int*   boff   = (int*)alloc((size_t)SCAN_NBLK * 4);
    int2*  sedge  = (int2*)alloc((size_t)E2_ * 8);               // 6.8MB packed (src,eid)
    unsigned short* WT1 = (unsigned short*)alloc((size_t)256 * FIN * 2);  // 64KB
    unsigned short* WT2 = (unsigned short*)alloc((size_t)256 * FH * 2);   // 128KB
    unsigned short* bufC = (unsigned short*)alloc((size_t)N_ * 256 * 2);  // 25.6MB bf16
    unsigned short* hbuf = (unsigned short*)alloc((size_t)N_ * 256 * 2);  // 25.6MB bf16
    unsigned char*  hbuf8 = (unsigned char*)alloc((size_t)N_ * 256);      // 12.8MB fp8
    unsigned short* bufB = (unsigned short*)alloc((size_t)N_ * 256 * 2);  // 25.6MB bf16
    if (off > ws_size){ k_sentinel<<<1,1,0,stream>>>(out, 5555.f); return; }

    float* ssum = stats;
    float* ssq  = stats + 256;
    const int GX = cdiv(N_, 64);    // 782
    const int NB4 = cdiv(N_ * 4, 256);

    // ---- CSR build (shared by both layers) ----
    k_zero32<<<cdiv(N_,256),256,0,stream>>>((unsigned*)counts, N_);
    k_zero32<<<cdiv(N_,256),256,0,stream>>>((unsigned*)cursor, N_);
    k_count<<<cdiv(E2_,256),256,0,stream>>>(ei, counts);
    k_scan_local<<<SCAN_NBLK,256,0,stream>>>(counts, rs, bsum);
    k_scan_block<<<1,256,0,stream>>>(bsum, boff, rs);
    k_scan_add<<<SCAN_NBLK,256,0,stream>>>(rs, boff);
    k_scatter<<<cdiv(E2_,256),256,0,stream>>>(ei, rs, cursor, sedge);

    // ---- shared precompute ----
    k_zero32<<<2,256,0,stream>>>((unsigned*)stats, 512);
    k_attr_sum<<<ATTR_NBLK,256,0,stream>>>(ea, apart);
    k_attr_fin<<<1,256,0,stream>>>(apart, asum);
    k_w2t<<<FIN,256,0,stream>>>(W1, WT1, FIN);
    k_w2t<<<FH,256,0,stream>>>(W2, WT2, FH);

    // ---- BN1 + lrelu (fp32 -> bf16) ----
    k_bn_stats<<<256,256,0,stream>>>(x, FIN, ssum, ssq);
    k_bn_apply_bf<<<2048,256,0,stream>>>(x, ssum, ssq, bn1g, bn1b, bufC, FIN);

    // ---- GAT layer 1 ----
    k_gemm_mfma<<<dim3(GX,4),256,0,stream>>>(bufC, WT1, hbuf, hbuf8, N_, FIN);
    k_al<<<cdiv(N_,4),256,0,stream>>>(hbuf, as1, ad1, als, ald);
    k_prep<<<1,64,0,stream>>>(We1, ae1, asum, Vbuf, alloop);
    k_al_edge<<<cdiv(E_*4,256),256,0,stream>>>(ea, Vbuf, ale);
    k_smax<<<NB4,256,0,stream>>>(rs, sedge, als, ald, ale, alloop, mxden);
    k_aggregate4<true><<<cdiv(N_,4),256,0,stream>>>(hbuf8, als, ald, ale, alloop, mxden,
                                                    rs, sedge, b1, bufB);

    // ---- BN2 + lrelu (bf16 -> bf16) ----
    k_zero32<<<2,256,0,stream>>>((unsigned*)stats, 512);
    k_bn_stats_b16<<<256,256,0,stream>>>(bufB, FH, ssum, ssq);
    k_bn_apply_b16<<<2048,256,0,stream>>>(bufB, ssum, ssq, bn2g, bn2b, bufC, FH);

    // ---- GAT layer 2 ----
    k_gemm_mfma<<<dim3(GX,4),256,0,stream>>>(bufC, WT2, hbuf, hbuf8, N_, FH);
    k_al<<<cdiv(N_,4),256,0,stream>>>(hbuf, as2, ad2, als, ald);
    k_prep<<<1,64,0,stream>>>(We2, ae2, asum, Vbuf, alloop);
    k_al_edge<<<cdiv(E_*4,256),256,0,stream>>>(ea, Vbuf, ale);
    k_smax<<<NB4,256,0,stream>>>(rs, sedge, als, ald, ale, alloop, mxden);
    k_aggregate4<false><<<cdiv(N_,4),256,0,stream>>>(hbuf8, als, ald, ale, alloop, mxden,
                                                     rs, sedge, b2, out);

    // ---- edge_index passthrough ----
    k_edge_store<<<cdiv((int)OUT1,256),256,0,stream>>>(ei, out + OUT0);
}

// Round 16
// 467.668 us; speedup vs baseline: 1.1239x; 1.1239x over previous
//
#include <hip/hip_runtime.h>
#include <hip/hip_bf16.h>

// Problem constants
constexpr int N_  = 50000;
constexpr int E_  = 800000;
constexpr int E2_ = 850000;   // E + N self loops
constexpr int FIN = 128;
constexpr int FH  = 256;      // H * C = 4 * 64
constexpr float BN_EPS = 1e-5f;
constexpr float NEG_ATT = 0.2f;
constexpr float NEG_OUT = 0.1f;
constexpr size_t OUT0 = (size_t)N_ * FH;   // 12.8M feature elems (fp32)
constexpr size_t OUT1 = (size_t)2 * E_;    // 1.6M edge elems (fp32)
constexpr int SCAN_NBLK = (N_ + 255) / 256;   // 196
constexpr int ATTR_NBLK = 1024;

static inline int cdiv(int a, int b){ return (a + b - 1) / b; }

using short8 = __attribute__((ext_vector_type(8))) short;
using f32x4  = __attribute__((ext_vector_type(4))) float;
using f32x2  = __attribute__((ext_vector_type(2))) float;

#if __has_builtin(__builtin_amdgcn_cvt_pk_f32_fp8) && __has_builtin(__builtin_amdgcn_cvt_pk_fp8_f32)
#define FP8_HW 1
#else
#define FP8_HW 0
#endif

__device__ inline float lrelu(float v, float ns){ return v > 0.f ? v : ns * v; }

__device__ inline unsigned short bf16rne(float f){
    unsigned u = __float_as_uint(f);
    u += 0x7fffu + ((u >> 16) & 1u);
    return (unsigned short)(u >> 16);
}
__device__ inline float bf16lo(unsigned u){ return __uint_as_float(u << 16); }
__device__ inline float bf16hi(unsigned u){ return __uint_as_float(u & 0xffff0000u); }
__device__ inline float bf16f(unsigned short v){ return __uint_as_float((unsigned)v << 16); }

// ---- software e4m3fn codec (fallback only; HW cvt used when available) ----
__device__ inline float fp8dec1(unsigned b){
    unsigned s = b >> 7;
    unsigned e = (b >> 3) & 15;
    unsigned m = b & 7;
    float v;
    if (e == 0) v = (float)m * 0.001953125f;           // m * 2^-9
    else        v = __uint_as_float(((e + 120u) << 23) | (m << 20));
    return s ? -v : v;
}
__device__ inline unsigned fp8enc1(float f){
    unsigned u = __float_as_uint(f);
    unsigned s = (u >> 31) << 7;
    float af = fabsf(f);
    if (af >= 448.f) return s | 0x7Eu;
    if (af < 0.0009765625f) return s;                   // < 2^-10 -> 0
    if (af < 0.015625f){                                // subnormal range
        int q = (int)(af * 512.f + 0.5f);               // round to m*2^-9
        return s | (unsigned)q;
    }
    unsigned a = u & 0x7fffffffu;
    a += 0x7FFFFu + ((a >> 20) & 1u);                   // RNE at mantissa bit 20
    int e8 = (int)(a >> 23) - 120;
    unsigned m8 = (a >> 20) & 7u;
    if (e8 > 15 || (e8 == 15 && m8 == 7u)) return s | 0x7Eu;
    return s | ((unsigned)e8 << 3) | m8;
}
__device__ inline void dec4(unsigned g, float& f0, float& f1, float& f2, float& f3){
#if FP8_HW
    f32x2 lo = __builtin_amdgcn_cvt_pk_f32_fp8((int)g, false);
    f32x2 hi = __builtin_amdgcn_cvt_pk_f32_fp8((int)g, true);
    f0 = lo[0]; f1 = lo[1]; f2 = hi[0]; f3 = hi[1];
#else
    f0 = fp8dec1(g & 255u); f1 = fp8dec1((g >> 8) & 255u);
    f2 = fp8dec1((g >> 16) & 255u); f3 = fp8dec1(g >> 24);
#endif
}
__device__ inline unsigned char fp8b(float f){
#if FP8_HW
    return (unsigned char)(__builtin_amdgcn_cvt_pk_fp8_f32(f, f, 0, false) & 0xff);
#else
    return (unsigned char)fp8enc1(f);
#endif
}

__global__ void k_sentinel(float* out, float v){ out[0] = v; }

__global__ void k_zero32(unsigned* p, int n){
    int i = blockIdx.x * blockDim.x + threadIdx.x;
    if (i < n) p[i] = 0u;
}

// ---------- W [K][256] fp32 -> WT [256][K] bf16 ----------
__global__ void k_w2t(const float* __restrict__ W, unsigned short* __restrict__ WT, int K){
    int i = blockIdx.x * blockDim.x + threadIdx.x;
    if (i >= K * 256) return;
    int k = i >> 8, c = i & 255;
    WT[(size_t)c * K + k] = bf16rne(W[i]);
}

// ---------- BatchNorm stats (fp32 input) ----------
__global__ void k_bn_stats(const float* __restrict__ x, int F,
                           float* __restrict__ sum, float* __restrict__ sumsq){
    int gid = blockIdx.x * blockDim.x + threadIdx.x;
    int T = gridDim.x * blockDim.x;      // 65536
    int c = gid % F;
    int r0 = gid / F;
    int rstep = T / F;
    float s = 0.f, s2 = 0.f;
    for (int r = r0; r < N_; r += rstep){
        float v = x[(size_t)r * F + c];
        s += v; s2 += v * v;
    }
    atomicAdd(&sum[c], s);
    atomicAdd(&sumsq[c], s2);
}

// ---------- BatchNorm stats (bf16 input) ----------
__global__ void k_bn_stats_b16(const unsigned short* __restrict__ x, int F,
                               float* __restrict__ sum, float* __restrict__ sumsq){
    int gid = blockIdx.x * blockDim.x + threadIdx.x;
    int T = gridDim.x * blockDim.x;
    int c = gid % F;
    int r0 = gid / F;
    int rstep = T / F;
    float s = 0.f, s2 = 0.f;
    for (int r = r0; r < N_; r += rstep){
        float v = bf16f(x[(size_t)r * F + c]);
        s += v; s2 += v * v;
    }
    atomicAdd(&sum[c], s);
    atomicAdd(&sumsq[c], s2);
}

// BN + lrelu, fp32 in -> bf16 out
__global__ void k_bn_apply_bf(const float* __restrict__ x, const float* __restrict__ sum,
                              const float* __restrict__ sumsq, const float* __restrict__ gamma,
                              const float* __restrict__ beta, unsigned short* __restrict__ out, int F){
    size_t tot = (size_t)N_ * F;
    size_t step = (size_t)gridDim.x * blockDim.x;
    for (size_t i = blockIdx.x * (size_t)blockDim.x + threadIdx.x; i < tot; i += step){
        int c = (int)(i % F);
        float mean = sum[c] / (float)N_;
        float var = sumsq[c] / (float)N_ - mean * mean;
        float v = (x[i] - mean) * rsqrtf(var + BN_EPS) * gamma[c] + beta[c];
        out[i] = bf16rne(lrelu(v, NEG_OUT));
    }
}

// BN + lrelu, bf16 in -> bf16 out
__global__ void k_bn_apply_b16(const unsigned short* __restrict__ x, const float* __restrict__ sum,
                               const float* __restrict__ sumsq, const float* __restrict__ gamma,
                               const float* __restrict__ beta, unsigned short* __restrict__ out, int F){
    size_t tot = (size_t)N_ * F;
    size_t step = (size_t)gridDim.x * blockDim.x;
    for (size_t i = blockIdx.x * (size_t)blockDim.x + threadIdx.x; i < tot; i += step){
        int c = (int)(i % F);
        float mean = sum[c] / (float)N_;
        float var = sumsq[c] / (float)N_ - mean * mean;
        float v = (bf16f(x[i]) - mean) * rsqrtf(var + BN_EPS) * gamma[c] + beta[c];
        out[i] = bf16rne(lrelu(v, NEG_OUT));
    }
}

// ---------- MFMA GEMM: C[M x 256] = A[M x K] @ B[K x 256]; writes bf16 + fp8 copies ----------
__global__ __launch_bounds__(256) void k_gemm_mfma(const unsigned short* __restrict__ A,
                                                   const unsigned short* __restrict__ WT,
                                                   unsigned short* __restrict__ C,
                                                   unsigned char* __restrict__ C8, int M, int K){
    __shared__ unsigned short Al[64][32];   // 4KB
    __shared__ unsigned short Bl[64][32];   // 4KB  (Bl[col][k])
    int tid = threadIdx.x;
    int w = tid >> 6;
    int l = tid & 63;
    int row0 = blockIdx.x * 64;
    int col0 = blockIdx.y * 64;
    f32x4 acc[4];
    #pragma unroll
    for (int m = 0; m < 4; ++m) acc[m] = (f32x4){0.f, 0.f, 0.f, 0.f};

    int srow = tid >> 2;
    int skq  = (tid & 3) * 8;

    for (int k0 = 0; k0 < K; k0 += 32){
        {
            short8 v = {0,0,0,0,0,0,0,0};
            if (row0 + srow < M)
                v = *reinterpret_cast<const short8*>(A + (size_t)(row0 + srow) * K + k0 + skq);
            *reinterpret_cast<short8*>(&Al[srow][skq]) = v;
        }
        {
            short8 v = *reinterpret_cast<const short8*>(WT + (size_t)(col0 + srow) * K + k0 + skq);
            *reinterpret_cast<short8*>(&Bl[srow][skq]) = v;
        }
        __syncthreads();
        short8 b = *reinterpret_cast<const short8*>(&Bl[w * 16 + (l & 15)][8 * (l >> 4)]);
        #pragma unroll
        for (int m = 0; m < 4; ++m){
            short8 a = *reinterpret_cast<const short8*>(&Al[m * 16 + (l & 15)][8 * (l >> 4)]);
            acc[m] = __builtin_amdgcn_mfma_f32_16x16x32_bf16(a, b, acc[m], 0, 0, 0);
        }
        __syncthreads();
    }
    int ccol = col0 + w * 16 + (l & 15);
    #pragma unroll
    for (int m = 0; m < 4; ++m){
        #pragma unroll
        for (int r = 0; r < 4; ++r){
            int row = row0 + m * 16 + (l >> 4) * 4 + r;
            if (row < M){
                float f = acc[m][r];
                C[(size_t)row * 256 + ccol]  = bf16rne(f);
                C8[(size_t)row * 256 + ccol] = fp8b(f);
            }
        }
    }
}

// ---------- per-node attention terms: one wave per node, bf16 h ----------
__global__ __launch_bounds__(256) void k_al(const unsigned short* __restrict__ hb,
                                            const float* __restrict__ asrc,
                                            const float* __restrict__ adst,
                                            float* __restrict__ als, float* __restrict__ ald){
    int n = blockIdx.x * 4 + (threadIdx.x >> 6);
    if (n >= N_) return;
    int lane = threadIdx.x & 63;
    uint2 g = *reinterpret_cast<const uint2*>(hb + (size_t)n * 256 + lane * 4);
    float h0 = bf16lo(g.x), h1 = bf16hi(g.x), h2 = bf16lo(g.y), h3 = bf16hi(g.y);
    float4 as = *reinterpret_cast<const float4*>(asrc + lane * 4);
    float4 ad = *reinterpret_cast<const float4*>(adst + lane * 4);
    float ps = h0*as.x + h1*as.y + h2*as.z + h3*as.w;
    float pd = h0*ad.x + h1*ad.y + h2*ad.z + h3*ad.w;
    #pragma unroll
    for (int m = 1; m < 16; m <<= 1){
        ps += __shfl_xor(ps, m, 64);
        pd += __shfl_xor(pd, m, 64);
    }
    if ((lane & 15) == 0){
        int hd = lane >> 4;
        als[(size_t)n*4 + hd] = ps;
        ald[(size_t)n*4 + hd] = pd;
    }
}

// ---------- edge_attr column sums: block partials (NO global atomics) ----------
__global__ __launch_bounds__(256) void k_attr_sum(const float* __restrict__ ea,
                                                  float* __restrict__ part){
    __shared__ float4 sdata[256];
    int tid = threadIdx.x;
    const float4* p = reinterpret_cast<const float4*>(ea);
    size_t step = (size_t)gridDim.x * 256;
    size_t end = (size_t)E_ * 4;
    size_t j = (size_t)blockIdx.x * 256 + tid;
    float4 a0 = make_float4(0.f,0.f,0.f,0.f), a1 = a0, a2 = a0, a3 = a0;
    for (; j + 3 * step < end; j += 4 * step){
        float4 v0 = p[j], v1 = p[j + step], v2 = p[j + 2*step], v3 = p[j + 3*step];
        a0.x += v0.x; a0.y += v0.y; a0.z += v0.z; a0.w += v0.w;
        a1.x += v1.x; a1.y += v1.y; a1.z += v1.z; a1.w += v1.w;
        a2.x += v2.x; a2.y += v2.y; a2.z += v2.z; a2.w += v2.w;
        a3.x += v3.x; a3.y += v3.y; a3.z += v3.z; a3.w += v3.w;
    }
    for (; j < end; j += step){
        float4 v = p[j];
        a0.x += v.x; a0.y += v.y; a0.z += v.z; a0.w += v.w;
    }
    a0.x += a1.x + a2.x + a3.x;  a0.y += a1.y + a2.y + a3.y;
    a0.z += a1.z + a2.z + a3.z;  a0.w += a1.w + a2.w + a3.w;
    sdata[tid] = a0;
    __syncthreads();
    #pragma unroll
    for (int s = 128; s >= 4; s >>= 1){
        if (tid < s){
            float4 o = sdata[tid + s];
            float4 m = sdata[tid];
            m.x += o.x; m.y += o.y; m.z += o.z; m.w += o.w;
            sdata[tid] = m;
        }
        __syncthreads();
    }
    if (tid < 4){
        float4 m = sdata[tid];
        float* pp = part + (size_t)blockIdx.x * 16 + tid * 4;
        pp[0] = m.x; pp[1] = m.y; pp[2] = m.z; pp[3] = m.w;
    }
}

// final reduce of part[ATTR_NBLK][16] -> asum[16]
__global__ __launch_bounds__(256) void k_attr_fin(const float* __restrict__ part,
                                                  float* __restrict__ asum){
    __shared__ float sd[256];
    int t = threadIdx.x;
    int col = t & 15, seg = t >> 4;   // 16 segments
    float s = 0.f;
    for (int b = seg; b < ATTR_NBLK; b += 16) s += part[(size_t)b * 16 + col];
    sd[t] = s;
    __syncthreads();
    #pragma unroll
    for (int off = 128; off >= 16; off >>= 1){
        if (t < off) sd[t] += sd[t + off];
        __syncthreads();
    }
    if (t < 16) asum[t] = sd[t];
}

// ---------- V[k][h]; alloop[h] ----------
__global__ void k_prep(const float* __restrict__ We, const float* __restrict__ aedge,
                       const float* __restrict__ asum, float* __restrict__ V,
                       float* __restrict__ alloop){
    __shared__ float Vs[64];
    int t = threadIdx.x;  // 64 threads
    int k = t >> 2, hd = t & 3;
    float s = 0.f;
    for (int c = 0; c < 64; ++c) s += We[k * 256 + hd * 64 + c] * aedge[hd * 64 + c];
    Vs[t] = s;
    V[t] = s;
    __syncthreads();
    if (t < 4){
        float r = 0.f;
        for (int kk = 0; kk < 16; ++kk) r += (asum[kk] / (float)E_) * Vs[kk * 4 + t];
        alloop[t] = r;
    }
}

// ---------- al_edge ----------
__global__ void k_al_edge(const float* __restrict__ ea, const float* __restrict__ V,
                          float* __restrict__ ale){
    int idx = blockIdx.x * blockDim.x + threadIdx.x;   // E*4
    if (idx >= E_ * 4) return;
    int e = idx >> 2, hd = idx & 3;
    const float* ep = ea + (size_t)e * 16;
    float s = 0.f;
    #pragma unroll
    for (int k = 0; k < 16; ++k) s += ep[k] * V[k * 4 + hd];
    ale[idx] = s;
}

// ---------- CSR build ----------
__global__ void k_count(const int* __restrict__ ei, int* __restrict__ counts){
    int e = blockIdx.x * blockDim.x + threadIdx.x;
    if (e >= E2_) return;
    int d = (e < E_) ? ei[E_ + e] : (e - E_);
    atomicAdd(&counts[d], 1);
}

__global__ __launch_bounds__(256) void k_scan_local(const int* __restrict__ counts,
                                                    int* __restrict__ rs,
                                                    int* __restrict__ bsum){
    __shared__ int sd[256];
    int t = threadIdx.x;
    int idx = blockIdx.x * 256 + t;
    int c = (idx < N_) ? counts[idx] : 0;
    sd[t] = c;
    __syncthreads();
    #pragma unroll
    for (int off = 1; off < 256; off <<= 1){
        int o = (t >= off) ? sd[t - off] : 0;
        __syncthreads();
        sd[t] += o;
        __syncthreads();
    }
    if (idx < N_) rs[idx] = sd[t] - c;
    if (t == 255) bsum[blockIdx.x] = sd[255];
}

__global__ __launch_bounds__(256) void k_scan_block(const int* __restrict__ bsum,
                                                    int* __restrict__ boff,
                                                    int* __restrict__ rs){
    __shared__ int sd[256];
    int t = threadIdx.x;
    int v = (t < SCAN_NBLK) ? bsum[t] : 0;
    sd[t] = v;
    __syncthreads();
    #pragma unroll
    for (int off = 1; off < 256; off <<= 1){
        int o = (t >= off) ? sd[t - off] : 0;
        __syncthreads();
        sd[t] += o;
        __syncthreads();
    }
    if (t < SCAN_NBLK) boff[t] = sd[t] - v;
    if (t == 0) rs[N_] = E2_;
}

__global__ __launch_bounds__(256) void k_scan_add(int* __restrict__ rs,
                                                  const int* __restrict__ boff){
    int idx = blockIdx.x * 256 + threadIdx.x;
    if (idx < N_) rs[idx] += boff[blockIdx.x];
}

// scatter packed (src, eid) in ONE 8B store
__global__ void k_scatter(const int* __restrict__ ei, const int* __restrict__ rs,
                          int* __restrict__ cursor, int2* __restrict__ sedge){
    int e = blockIdx.x * blockDim.x + threadIdx.x;
    if (e >= E2_) return;
    int s, d;
    if (e < E_){ s = ei[e]; d = ei[E_ + e]; }
    else { s = e - E_; d = s; }
    int slot = rs[d] + atomicAdd(&cursor[d], 1);
    sedge[slot] = make_int2(s, e);
}

// ---------- one wave per dst node, FOUR independent edge streams, fp8 gather,
// online softmax per stream (round-14 verified design) ----------
#define MERGE4(OFF) { \
    float mo  = __shfl_xor(m,   OFF, 64); \
    float dno = __shfl_xor(den, OFF, 64); \
    float o0=__shfl_xor(a0,OFF,64), o1=__shfl_xor(a1,OFF,64), o2=__shfl_xor(a2,OFF,64), o3=__shfl_xor(a3,OFF,64); \
    float o4=__shfl_xor(a4,OFF,64), o5=__shfl_xor(a5,OFF,64), o6=__shfl_xor(a6,OFF,64), o7=__shfl_xor(a7,OFF,64); \
    float o8=__shfl_xor(a8,OFF,64), o9=__shfl_xor(a9,OFF,64), oA=__shfl_xor(aA,OFF,64), oB=__shfl_xor(aB,OFF,64); \
    float oC=__shfl_xor(aC,OFF,64), oD=__shfl_xor(aD,OFF,64), oE=__shfl_xor(aE,OFF,64), oF=__shfl_xor(aF,OFF,64); \
    float M = fmaxf(m, mo); \
    float sS = __expf(m - M), sO = __expf(mo - M); \
    den = den*sS + dno*sO; \
    a0=a0*sS+o0*sO; a1=a1*sS+o1*sO; a2=a2*sS+o2*sO; a3=a3*sS+o3*sO; \
    a4=a4*sS+o4*sO; a5=a5*sS+o5*sO; a6=a6*sS+o6*sO; a7=a7*sS+o7*sO; \
    a8=a8*sS+o8*sO; a9=a9*sS+o9*sO; aA=aA*sS+oA*sO; aB=aB*sS+oB*sO; \
    aC=aC*sS+oC*sO; aD=aD*sS+oD*sO; aE=aE*sS+oE*sO; aF=aF*sS+oF*sO; \
    m = M; }

template<bool BF16OUT>
__global__ __launch_bounds__(256) void k_aggregate4(const unsigned char* __restrict__ hb8,
        const float* __restrict__ als, const float* __restrict__ ald,
        const float* __restrict__ ale, const float* __restrict__ alloop,
        const int* __restrict__ rs, const int2* __restrict__ sedge,
        const float* __restrict__ bias, void* __restrict__ outp){
    int n = blockIdx.x * 4 + (threadIdx.x >> 6);
    if (n >= N_) return;
    int lane = threadIdx.x & 63;
    int q  = lane >> 4;
    int sl = lane & 15;
    int col0 = sl * 16;
    int hd = sl >> 2;
    float aldn = ald[(size_t)n * 4 + hd];
    float alp  = alloop[hd];
    int i0 = rs[n], i1 = rs[n + 1];
    float m = -3.0e38f, den = 0.f;
    float a0=0.f,a1=0.f,a2=0.f,a3=0.f,a4=0.f,a5=0.f,a6=0.f,a7=0.f;
    float a8=0.f,a9=0.f,aA=0.f,aB=0.f,aC=0.f,aD=0.f,aE=0.f,aF=0.f;
    for (int i = i0 + q; i < i1; i += 4){
        int2 se = sedge[i];
        int s   = se.x;
        int eid = se.y;
        float alE = (eid < E_) ? ale[(size_t)eid * 4 + hd] : alp;
        float lg = als[(size_t)s * 4 + hd] + aldn + alE;
        lg = lrelu(lg, NEG_ATT);
        float mn = fmaxf(m, lg);
        float sc = __expf(m - mn);
        float p  = __expf(lg - mn);
        den = den * sc + p;
        uint4 g = *reinterpret_cast<const uint4*>(hb8 + (size_t)s * 256 + col0);
        float t0, t1, t2, t3;
        dec4(g.x, t0, t1, t2, t3);
        a0 = a0*sc + p*t0;  a1 = a1*sc + p*t1;  a2 = a2*sc + p*t2;  a3 = a3*sc + p*t3;
        dec4(g.y, t0, t1, t2, t3);
        a4 = a4*sc + p*t0;  a5 = a5*sc + p*t1;  a6 = a6*sc + p*t2;  a7 = a7*sc + p*t3;
        dec4(g.z, t0, t1, t2, t3);
        a8 = a8*sc + p*t0;  a9 = a9*sc + p*t1;  aA = aA*sc + p*t2;  aB = aB*sc + p*t3;
        dec4(g.w, t0, t1, t2, t3);
        aC = aC*sc + p*t0;  aD = aD*sc + p*t1;  aE = aE*sc + p*t2;  aF = aF*sc + p*t3;
        m = mn;
    }
    MERGE4(16)
    MERGE4(32)
    float inv = 1.f / den;
    float v0, v1, v2, v3;
    if      (q == 0){ v0 = a0; v1 = a1; v2 = a2; v3 = a3; }
    else if (q == 1){ v0 = a4; v1 = a5; v2 = a6; v3 = a7; }
    else if (q == 2){ v0 = a8; v1 = a9; v2 = aA; v3 = aB; }
    else            { v0 = aC; v1 = aD; v2 = aE; v3 = aF; }
    int wc = col0 + q * 4;
    float4 b4 = *reinterpret_cast<const float4*>(bias + wc);
    float r0 = lrelu(v0 * inv + b4.x, NEG_OUT);
    float r1 = lrelu(v1 * inv + b4.y, NEG_OUT);
    float r2 = lrelu(v2 * inv + b4.z, NEG_OUT);
    float r3 = lrelu(v3 * inv + b4.w, NEG_OUT);
    if (BF16OUT){
        ushort4 pk;
        pk.x = bf16rne(r0); pk.y = bf16rne(r1); pk.z = bf16rne(r2); pk.w = bf16rne(r3);
        *reinterpret_cast<ushort4*>((unsigned short*)outp + (size_t)n * 256 + wc) = pk;
    } else {
        *reinterpret_cast<float4*>((float*)outp + (size_t)n * 256 + wc) =
            make_float4(r0, r1, r2, r3);
    }
}

// ---------- edge_index passthrough (fp32, bit-exact) ----------
__global__ void k_edge_store(const int* __restrict__ ei, float* __restrict__ out){
    int j = blockIdx.x * blockDim.x + threadIdx.x;     // 2E
    if (j >= (int)OUT1) return;
    out[j] = (float)ei[j];
}

extern "C" void kernel_launch(void* const* d_in, const int* in_sizes, int n_in,
                              void* d_out, int out_size, void* d_ws, size_t ws_size,
                              hipStream_t stream){
    const float* x    = (const float*)d_in[0];
    const int*   ei   = (const int*)d_in[1];
    const float* ea   = (const float*)d_in[2];
    const float* bn1g = (const float*)d_in[3];
    const float* bn1b = (const float*)d_in[4];
    const float* W1   = (const float*)d_in[5];
    const float* We1  = (const float*)d_in[6];
    const float* as1  = (const float*)d_in[7];
    const float* ad1  = (const float*)d_in[8];
    const float* ae1  = (const float*)d_in[9];
    const float* b1   = (const float*)d_in[10];
    const float* bn2g = (const float*)d_in[11];
    const float* bn2b = (const float*)d_in[12];
    const float* W2   = (const float*)d_in[13];
    const float* We2  = (const float*)d_in[14];
    const float* as2  = (const float*)d_in[15];
    const float* ad2  = (const float*)d_in[16];
    const float* ae2  = (const float*)d_in[17];
    const float* b2   = (const float*)d_in[18];
    float* out = (float*)d_out;

    bool ok = (n_in >= 19)
           && (in_sizes[0] == N_ * FIN)
           && (in_sizes[1] == 2 * E_)
           && (in_sizes[2] == E_ * 16)
           && (out_size == (int)(OUT0 + OUT1));
    if (!ok){ k_sentinel<<<1,1,0,stream>>>(out, 7777.f); return; }

    char* w = (char*)d_ws;
    size_t off = 0;
    auto alloc = [&](size_t bytes) -> void* {
        off = (off + 255) & ~(size_t)255;
        void* p = w + off;
        off += bytes;
        return p;
    };
    float* stats  = (float*)alloc(512 * 4);
    float* asum   = (float*)alloc(16 * 4);
    float* apart  = (float*)alloc((size_t)ATTR_NBLK * 16 * 4);   // 64KB
    float* Vbuf   = (float*)alloc(64 * 4);
    float* alloop = (float*)alloc(4 * 4);
    float* als    = (float*)alloc((size_t)N_ * 4 * 4);
    float* ald    = (float*)alloc((size_t)N_ * 4 * 4);
    float* ale    = (float*)alloc((size_t)E_ * 4 * 4);           // 12.8MB
    int*   rs     = (int*)alloc((size_t)(N_ + 1) * 4);
    int*   counts = (int*)alloc((size_t)N_ * 4);
    int*   cursor = (int*)alloc((size_t)N_ * 4);
    int*   bsum   = (int*)alloc((size_t)SCAN_NBLK * 4);
    int*   boff   = (int*)alloc((size_t)SCAN_NBLK * 4);
    int2*  sedge  = (int2*)alloc((size_t)E2_ * 8);               // 6.8MB packed (src,eid)
    unsigned short* WT1 = (unsigned short*)alloc((size_t)256 * FIN * 2);  // 64KB
    unsigned short* WT2 = (unsigned short*)alloc((size_t)256 * FH * 2);   // 128KB
    unsigned short* bufC = (unsigned short*)alloc((size_t)N_ * 256 * 2);  // 25.6MB bf16
    unsigned short* hbuf = (unsigned short*)alloc((size_t)N_ * 256 * 2);  // 25.6MB bf16
    unsigned char*  hbuf8 = (unsigned char*)alloc((size_t)N_ * 256);      // 12.8MB fp8
    unsigned short* bufB = (unsigned short*)alloc((size_t)N_ * 256 * 2);  // 25.6MB bf16
    if (off > ws_size){ k_sentinel<<<1,1,0,stream>>>(out, 5555.f); return; }

    float* ssum = stats;
    float* ssq  = stats + 256;
    const int GX = cdiv(N_, 64);    // 782

    // ---- CSR build (shared by both layers) ----
    k_zero32<<<cdiv(N_,256),256,0,stream>>>((unsigned*)counts, N_);
    k_zero32<<<cdiv(N_,256),256,0,stream>>>((unsigned*)cursor, N_);
    k_count<<<cdiv(E2_,256),256,0,stream>>>(ei, counts);
    k_scan_local<<<SCAN_NBLK,256,0,stream>>>(counts, rs, bsum);
    k_scan_block<<<1,256,0,stream>>>(bsum, boff, rs);
    k_scan_add<<<SCAN_NBLK,256,0,stream>>>(rs, boff);
    k_scatter<<<cdiv(E2_,256),256,0,stream>>>(ei, rs, cursor, sedge);

    // ---- shared precompute ----
    k_zero32<<<2,256,0,stream>>>((unsigned*)stats, 512);
    k_attr_sum<<<ATTR_NBLK,256,0,stream>>>(ea, apart);
    k_attr_fin<<<1,256,0,stream>>>(apart, asum);
    k_w2t<<<FIN,256,0,stream>>>(W1, WT1, FIN);
    k_w2t<<<FH,256,0,stream>>>(W2, WT2, FH);

    // ---- BN1 + lrelu (fp32 -> bf16) ----
    k_bn_stats<<<256,256,0,stream>>>(x, FIN, ssum, ssq);
    k_bn_apply_bf<<<2048,256,0,stream>>>(x, ssum, ssq, bn1g, bn1b, bufC, FIN);

    // ---- GAT layer 1 ----
    k_gemm_mfma<<<dim3(GX,4),256,0,stream>>>(bufC, WT1, hbuf, hbuf8, N_, FIN);
    k_al<<<cdiv(N_,4),256,0,stream>>>(hbuf, as1, ad1, als, ald);
    k_prep<<<1,64,0,stream>>>(We1, ae1, asum, Vbuf, alloop);
    k_al_edge<<<cdiv(E_*4,256),256,0,stream>>>(ea, Vbuf, ale);
    k_aggregate4<true><<<cdiv(N_,4),256,0,stream>>>(hbuf8, als, ald, ale, alloop,
                                                    rs, sedge, b1, bufB);

    // ---- BN2 + lrelu (bf16 -> bf16) ----
    k_zero32<<<2,256,0,stream>>>((unsigned*)stats, 512);
    k_bn_stats_b16<<<256,256,0,stream>>>(bufB, FH, ssum, ssq);
    k_bn_apply_b16<<<2048,256,0,stream>>>(bufB, ssum, ssq, bn2g, bn2b, bufC, FH);

    // ---- GAT layer 2 ----
    k_gemm_mfma<<<dim3(GX,4),256,0,stream>>>(bufC, WT2, hbuf, hbuf8, N_, FH);
    k_al<<<cdiv(N_,4),256,0,stream>>>(hbuf, as2, ad2, als, ald);
    k_prep<<<1,64,0,stream>>>(We2, ae2, asum, Vbuf, alloop);
    k_al_edge<<<cdiv(E_*4,256),256,0,stream>>>(ea, Vbuf, ale);
    k_aggregate4<false><<<cdiv(N_,4),256,0,stream>>>(hbuf8, als, ald, ale, alloop,
                                                     rs, sedge, b2, out);

    // ---- edge_index passthrough ----
    k_edge_store<<<cdiv((int)OUT1,256),256,0,stream>>>(ei, out + OUT0);
}

// Round 17
// 442.931 us; speedup vs baseline: 1.1867x; 1.0558x over previous
//
#include <hip/hip_runtime.h>
#include <hip/hip_bf16.h>

// Problem constants
constexpr int N_  = 50000;
constexpr int E_  = 800000;
constexpr int E2_ = 850000;   // E + N self loops
constexpr int FIN = 128;
constexpr int FH  = 256;      // H * C = 4 * 64
constexpr float BN_EPS = 1e-5f;
constexpr float NEG_ATT = 0.2f;
constexpr float NEG_OUT = 0.1f;
constexpr size_t OUT0 = (size_t)N_ * FH;   // 12.8M feature elems (fp32)
constexpr size_t OUT1 = (size_t)2 * E_;    // 1.6M edge elems (fp32)
constexpr int SCAN_NBLK = (N_ + 255) / 256;   // 196
constexpr int ATTR_NBLK = 1024;

static inline int cdiv(int a, int b){ return (a + b - 1) / b; }

using short8 = __attribute__((ext_vector_type(8))) short;
using f32x4  = __attribute__((ext_vector_type(4))) float;
using f32x2  = __attribute__((ext_vector_type(2))) float;

#if __has_builtin(__builtin_amdgcn_cvt_pk_f32_fp8) && __has_builtin(__builtin_amdgcn_cvt_pk_fp8_f32)
#define FP8_HW 1
#else
#define FP8_HW 0
#endif

__device__ inline float lrelu(float v, float ns){ return v > 0.f ? v : ns * v; }

__device__ inline unsigned short bf16rne(float f){
    unsigned u = __float_as_uint(f);
    u += 0x7fffu + ((u >> 16) & 1u);
    return (unsigned short)(u >> 16);
}
__device__ inline float bf16lo(unsigned u){ return __uint_as_float(u << 16); }
__device__ inline float bf16hi(unsigned u){ return __uint_as_float(u & 0xffff0000u); }
__device__ inline float bf16f(unsigned short v){ return __uint_as_float((unsigned)v << 16); }

// ---- software e4m3fn codec (fallback only; HW cvt used when available) ----
__device__ inline float fp8dec1(unsigned b){
    unsigned s = b >> 7;
    unsigned e = (b >> 3) & 15;
    unsigned m = b & 7;
    float v;
    if (e == 0) v = (float)m * 0.001953125f;           // m * 2^-9
    else        v = __uint_as_float(((e + 120u) << 23) | (m << 20));
    return s ? -v : v;
}
__device__ inline unsigned fp8enc1(float f){
    unsigned u = __float_as_uint(f);
    unsigned s = (u >> 31) << 7;
    float af = fabsf(f);
    if (af >= 448.f) return s | 0x7Eu;
    if (af < 0.0009765625f) return s;                   // < 2^-10 -> 0
    if (af < 0.015625f){                                // subnormal range
        int q = (int)(af * 512.f + 0.5f);               // round to m*2^-9
        return s | (unsigned)q;
    }
    unsigned a = u & 0x7fffffffu;
    a += 0x7FFFFu + ((a >> 20) & 1u);                   // RNE at mantissa bit 20
    int e8 = (int)(a >> 23) - 120;
    unsigned m8 = (a >> 20) & 7u;
    if (e8 > 15 || (e8 == 15 && m8 == 7u)) return s | 0x7Eu;
    return s | ((unsigned)e8 << 3) | m8;
}
__device__ inline void dec4(unsigned g, float& f0, float& f1, float& f2, float& f3){
#if FP8_HW
    f32x2 lo = __builtin_amdgcn_cvt_pk_f32_fp8((int)g, false);
    f32x2 hi = __builtin_amdgcn_cvt_pk_f32_fp8((int)g, true);
    f0 = lo[0]; f1 = lo[1]; f2 = hi[0]; f3 = hi[1];
#else
    f0 = fp8dec1(g & 255u); f1 = fp8dec1((g >> 8) & 255u);
    f2 = fp8dec1((g >> 16) & 255u); f3 = fp8dec1(g >> 24);
#endif
}
__device__ inline unsigned char fp8b(float f){
#if FP8_HW
    return (unsigned char)(__builtin_amdgcn_cvt_pk_fp8_f32(f, f, 0, false) & 0xff);
#else
    return (unsigned char)fp8enc1(f);
#endif
}

__global__ void k_sentinel(float* out, float v){ out[0] = v; }

__global__ void k_zero32(unsigned* p, int n){
    int i = blockIdx.x * blockDim.x + threadIdx.x;
    if (i < n) p[i] = 0u;
}

// ---------- W [K][256] fp32 -> WT [256][K] bf16 ----------
__global__ void k_w2t(const float* __restrict__ W, unsigned short* __restrict__ WT, int K){
    int i = blockIdx.x * blockDim.x + threadIdx.x;
    if (i >= K * 256) return;
    int k = i >> 8, c = i & 255;
    WT[(size_t)c * K + k] = bf16rne(W[i]);
}

// ---------- BatchNorm stats (fp32 input) ----------
__global__ void k_bn_stats(const float* __restrict__ x, int F,
                           float* __restrict__ sum, float* __restrict__ sumsq){
    int gid = blockIdx.x * blockDim.x + threadIdx.x;
    int T = gridDim.x * blockDim.x;      // 65536
    int c = gid % F;
    int r0 = gid / F;
    int rstep = T / F;
    float s = 0.f, s2 = 0.f;
    for (int r = r0; r < N_; r += rstep){
        float v = x[(size_t)r * F + c];
        s += v; s2 += v * v;
    }
    atomicAdd(&sum[c], s);
    atomicAdd(&sumsq[c], s2);
}

// ---------- BatchNorm stats (bf16 input) ----------
__global__ void k_bn_stats_b16(const unsigned short* __restrict__ x, int F,
                               float* __restrict__ sum, float* __restrict__ sumsq){
    int gid = blockIdx.x * blockDim.x + threadIdx.x;
    int T = gridDim.x * blockDim.x;
    int c = gid % F;
    int r0 = gid / F;
    int rstep = T / F;
    float s = 0.f, s2 = 0.f;
    for (int r = r0; r < N_; r += rstep){
        float v = bf16f(x[(size_t)r * F + c]);
        s += v; s2 += v * v;
    }
    atomicAdd(&sum[c], s);
    atomicAdd(&sumsq[c], s2);
}

// ---------- BN affine params: scale = gamma*rsqrt(var+eps), shift = beta - mean*scale ----------
__global__ void k_bnp(const float* __restrict__ sum, const float* __restrict__ sumsq,
                      const float* __restrict__ gamma, const float* __restrict__ beta,
                      float* __restrict__ scale, float* __restrict__ shift, int F){
    int c = blockIdx.x * blockDim.x + threadIdx.x;
    if (c >= F) return;
    float mean = sum[c] / (float)N_;
    float var = sumsq[c] / (float)N_ - mean * mean;
    float sc = gamma[c] * rsqrtf(var + BN_EPS);
    scale[c] = sc;
    shift[c] = beta[c] - mean * sc;
}

// ---------- MFMA GEMM with fused BN+lrelu on A: C = lrelu(BN(A)) @ B ----------
// A is fp32 (layer 1: x) or bf16 (layer 2: bufB). Writes bf16 + fp8 copies.
template<bool AFP32>
__global__ __launch_bounds__(256) void k_gemm_bn(const void* __restrict__ Ap,
        const unsigned short* __restrict__ WT,
        const float* __restrict__ scale, const float* __restrict__ shift,
        unsigned short* __restrict__ C, unsigned char* __restrict__ C8, int M, int K){
    __shared__ unsigned short Al[64][32];   // 4KB
    __shared__ unsigned short Bl[64][32];   // 4KB  (Bl[col][k])
    int tid = threadIdx.x;
    int w = tid >> 6;
    int l = tid & 63;
    int row0 = blockIdx.x * 64;
    int col0 = blockIdx.y * 64;
    f32x4 acc[4];
    #pragma unroll
    for (int m = 0; m < 4; ++m) acc[m] = (f32x4){0.f, 0.f, 0.f, 0.f};

    int srow = tid >> 2;
    int skq  = (tid & 3) * 8;

    for (int k0 = 0; k0 < K; k0 += 32){
        {   // stage A tile with fused BN + lrelu
            int row = row0 + srow;
            float f0=0.f,f1=0.f,f2=0.f,f3=0.f,f4=0.f,f5=0.f,f6=0.f,f7=0.f;
            if (row < M){
                int cbase = k0 + skq;
                if (AFP32){
                    const float* Af = (const float*)Ap + (size_t)row * K + cbase;
                    float4 u0 = *reinterpret_cast<const float4*>(Af);
                    float4 u1 = *reinterpret_cast<const float4*>(Af + 4);
                    f0=u0.x; f1=u0.y; f2=u0.z; f3=u0.w;
                    f4=u1.x; f5=u1.y; f6=u1.z; f7=u1.w;
                } else {
                    const unsigned short* Ab = (const unsigned short*)Ap + (size_t)row * K + cbase;
                    uint4 g = *reinterpret_cast<const uint4*>(Ab);
                    f0=bf16lo(g.x); f1=bf16hi(g.x); f2=bf16lo(g.y); f3=bf16hi(g.y);
                    f4=bf16lo(g.z); f5=bf16hi(g.z); f6=bf16lo(g.w); f7=bf16hi(g.w);
                }
                float4 s0 = *reinterpret_cast<const float4*>(scale + cbase);
                float4 s1 = *reinterpret_cast<const float4*>(scale + cbase + 4);
                float4 h0 = *reinterpret_cast<const float4*>(shift + cbase);
                float4 h1 = *reinterpret_cast<const float4*>(shift + cbase + 4);
                f0 = lrelu(f0*s0.x + h0.x, NEG_OUT); f1 = lrelu(f1*s0.y + h0.y, NEG_OUT);
                f2 = lrelu(f2*s0.z + h0.z, NEG_OUT); f3 = lrelu(f3*s0.w + h0.w, NEG_OUT);
                f4 = lrelu(f4*s1.x + h1.x, NEG_OUT); f5 = lrelu(f5*s1.y + h1.y, NEG_OUT);
                f6 = lrelu(f6*s1.z + h1.z, NEG_OUT); f7 = lrelu(f7*s1.w + h1.w, NEG_OUT);
            }
            short8 v;
            v[0]=(short)bf16rne(f0); v[1]=(short)bf16rne(f1);
            v[2]=(short)bf16rne(f2); v[3]=(short)bf16rne(f3);
            v[4]=(short)bf16rne(f4); v[5]=(short)bf16rne(f5);
            v[6]=(short)bf16rne(f6); v[7]=(short)bf16rne(f7);
            *reinterpret_cast<short8*>(&Al[srow][skq]) = v;
        }
        {   // stage B tile
            short8 v = *reinterpret_cast<const short8*>(WT + (size_t)(col0 + srow) * K + k0 + skq);
            *reinterpret_cast<short8*>(&Bl[srow][skq]) = v;
        }
        __syncthreads();
        short8 b = *reinterpret_cast<const short8*>(&Bl[w * 16 + (l & 15)][8 * (l >> 4)]);
        #pragma unroll
        for (int m = 0; m < 4; ++m){
            short8 a = *reinterpret_cast<const short8*>(&Al[m * 16 + (l & 15)][8 * (l >> 4)]);
            acc[m] = __builtin_amdgcn_mfma_f32_16x16x32_bf16(a, b, acc[m], 0, 0, 0);
        }
        __syncthreads();
    }
    int ccol = col0 + w * 16 + (l & 15);
    #pragma unroll
    for (int m = 0; m < 4; ++m){
        #pragma unroll
        for (int r = 0; r < 4; ++r){
            int row = row0 + m * 16 + (l >> 4) * 4 + r;
            if (row < M){
                float f = acc[m][r];
                C[(size_t)row * 256 + ccol]  = bf16rne(f);
                C8[(size_t)row * 256 + ccol] = fp8b(f);
            }
        }
    }
}

// ---------- per-node attention terms: one wave per node, bf16 h ----------
__global__ __launch_bounds__(256) void k_al(const unsigned short* __restrict__ hb,
                                            const float* __restrict__ asrc,
                                            const float* __restrict__ adst,
                                            float* __restrict__ als, float* __restrict__ ald){
    int n = blockIdx.x * 4 + (threadIdx.x >> 6);
    if (n >= N_) return;
    int lane = threadIdx.x & 63;
    uint2 g = *reinterpret_cast<const uint2*>(hb + (size_t)n * 256 + lane * 4);
    float h0 = bf16lo(g.x), h1 = bf16hi(g.x), h2 = bf16lo(g.y), h3 = bf16hi(g.y);
    float4 as = *reinterpret_cast<const float4*>(asrc + lane * 4);
    float4 ad = *reinterpret_cast<const float4*>(adst + lane * 4);
    float ps = h0*as.x + h1*as.y + h2*as.z + h3*as.w;
    float pd = h0*ad.x + h1*ad.y + h2*ad.z + h3*ad.w;
    #pragma unroll
    for (int m = 1; m < 16; m <<= 1){
        ps += __shfl_xor(ps, m, 64);
        pd += __shfl_xor(pd, m, 64);
    }
    if ((lane & 15) == 0){
        int hd = lane >> 4;
        als[(size_t)n*4 + hd] = ps;
        ald[(size_t)n*4 + hd] = pd;
    }
}

// ---------- edge_attr column sums: block partials (NO global atomics) ----------
__global__ __launch_bounds__(256) void k_attr_sum(const float* __restrict__ ea,
                                                  float* __restrict__ part){
    __shared__ float4 sdata[256];
    int tid = threadIdx.x;
    const float4* p = reinterpret_cast<const float4*>(ea);
    size_t step = (size_t)gridDim.x * 256;
    size_t end = (size_t)E_ * 4;
    size_t j = (size_t)blockIdx.x * 256 + tid;
    float4 a0 = make_float4(0.f,0.f,0.f,0.f), a1 = a0, a2 = a0, a3 = a0;
    for (; j + 3 * step < end; j += 4 * step){
        float4 v0 = p[j], v1 = p[j + step], v2 = p[j + 2*step], v3 = p[j + 3*step];
        a0.x += v0.x; a0.y += v0.y; a0.z += v0.z; a0.w += v0.w;
        a1.x += v1.x; a1.y += v1.y; a1.z += v1.z; a1.w += v1.w;
        a2.x += v2.x; a2.y += v2.y; a2.z += v2.z; a2.w += v2.w;
        a3.x += v3.x; a3.y += v3.y; a3.z += v3.z; a3.w += v3.w;
    }
    for (; j < end; j += step){
        float4 v = p[j];
        a0.x += v.x; a0.y += v.y; a0.z += v.z; a0.w += v.w;
    }
    a0.x += a1.x + a2.x + a3.x;  a0.y += a1.y + a2.y + a3.y;
    a0.z += a1.z + a2.z + a3.z;  a0.w += a1.w + a2.w + a3.w;
    sdata[tid] = a0;
    __syncthreads();
    #pragma unroll
    for (int s = 128; s >= 4; s >>= 1){
        if (tid < s){
            float4 o = sdata[tid + s];
            float4 m = sdata[tid];
            m.x += o.x; m.y += o.y; m.z += o.z; m.w += o.w;
            sdata[tid] = m;
        }
        __syncthreads();
    }
    if (tid < 4){
        float4 m = sdata[tid];
        float* pp = part + (size_t)blockIdx.x * 16 + tid * 4;
        pp[0] = m.x; pp[1] = m.y; pp[2] = m.z; pp[3] = m.w;
    }
}

// final reduce of part[ATTR_NBLK][16] -> asum[16]
__global__ __launch_bounds__(256) void k_attr_fin(const float* __restrict__ part,
                                                  float* __restrict__ asum){
    __shared__ float sd[256];
    int t = threadIdx.x;
    int col = t & 15, seg = t >> 4;   // 16 segments
    float s = 0.f;
    for (int b = seg; b < ATTR_NBLK; b += 16) s += part[(size_t)b * 16 + col];
    sd[t] = s;
    __syncthreads();
    #pragma unroll
    for (int off = 128; off >= 16; off >>= 1){
        if (t < off) sd[t] += sd[t + off];
        __syncthreads();
    }
    if (t < 16) asum[t] = sd[t];
}

// ---------- V[k][h]; alloop[h] ----------
__global__ void k_prep(const float* __restrict__ We, const float* __restrict__ aedge,
                       const float* __restrict__ asum, float* __restrict__ V,
                       float* __restrict__ alloop){
    __shared__ float Vs[64];
    int t = threadIdx.x;  // 64 threads
    int k = t >> 2, hd = t & 3;
    float s = 0.f;
    for (int c = 0; c < 64; ++c) s += We[k * 256 + hd * 64 + c] * aedge[hd * 64 + c];
    Vs[t] = s;
    V[t] = s;
    __syncthreads();
    if (t < 4){
        float r = 0.f;
        for (int kk = 0; kk < 16; ++kk) r += (asum[kk] / (float)E_) * Vs[kk * 4 + t];
        alloop[t] = r;
    }
}

// ---------- al_edge ----------
__global__ void k_al_edge(const float* __restrict__ ea, const float* __restrict__ V,
                          float* __restrict__ ale){
    int idx = blockIdx.x * blockDim.x + threadIdx.x;   // E*4
    if (idx >= E_ * 4) return;
    int e = idx >> 2, hd = idx & 3;
    const float* ep = ea + (size_t)e * 16;
    float s = 0.f;
    #pragma unroll
    for (int k = 0; k < 16; ++k) s += ep[k] * V[k * 4 + hd];
    ale[idx] = s;
}

// ---------- CSR build ----------
__global__ void k_count(const int* __restrict__ ei, int* __restrict__ counts){
    int e = blockIdx.x * blockDim.x + threadIdx.x;
    if (e >= E2_) return;
    int d = (e < E_) ? ei[E_ + e] : (e - E_);
    atomicAdd(&counts[d], 1);
}

__global__ __launch_bounds__(256) void k_scan_local(const int* __restrict__ counts,
                                                    int* __restrict__ rs,
                                                    int* __restrict__ bsum){
    __shared__ int sd[256];
    int t = threadIdx.x;
    int idx = blockIdx.x * 256 + t;
    int c = (idx < N_) ? counts[idx] : 0;
    sd[t] = c;
    __syncthreads();
    #pragma unroll
    for (int off = 1; off < 256; off <<= 1){
        int o = (t >= off) ? sd[t - off] : 0;
        __syncthreads();
        sd[t] += o;
        __syncthreads();
    }
    if (idx < N_) rs[idx] = sd[t] - c;
    if (t == 255) bsum[blockIdx.x] = sd[255];
}

__global__ __launch_bounds__(256) void k_scan_block(const int* __restrict__ bsum,
                                                    int* __restrict__ boff,
                                                    int* __restrict__ rs){
    __shared__ int sd[256];
    int t = threadIdx.x;
    int v = (t < SCAN_NBLK) ? bsum[t] : 0;
    sd[t] = v;
    __syncthreads();
    #pragma unroll
    for (int off = 1; off < 256; off <<= 1){
        int o = (t >= off) ? sd[t - off] : 0;
        __syncthreads();
        sd[t] += o;
        __syncthreads();
    }
    if (t < SCAN_NBLK) boff[t] = sd[t] - v;
    if (t == 0) rs[N_] = E2_;
}

__global__ __launch_bounds__(256) void k_scan_add(int* __restrict__ rs,
                                                  const int* __restrict__ boff){
    int idx = blockIdx.x * 256 + threadIdx.x;
    if (idx < N_) rs[idx] += boff[blockIdx.x];
}

// scatter packed (src, eid) in ONE 8B store
__global__ void k_scatter(const int* __restrict__ ei, const int* __restrict__ rs,
                          int* __restrict__ cursor, int2* __restrict__ sedge){
    int e = blockIdx.x * blockDim.x + threadIdx.x;
    if (e >= E2_) return;
    int s, d;
    if (e < E_){ s = ei[e]; d = ei[E_ + e]; }
    else { s = e - E_; d = s; }
    int slot = rs[d] + atomicAdd(&cursor[d], 1);
    sedge[slot] = make_int2(s, e);
}

// ---------- one wave per dst node, FOUR independent edge streams, fp8 gather,
// online softmax per stream (round-14 verified design) ----------
#define MERGE4(OFF) { \
    float mo  = __shfl_xor(m,   OFF, 64); \
    float dno = __shfl_xor(den, OFF, 64); \
    float o0=__shfl_xor(a0,OFF,64), o1=__shfl_xor(a1,OFF,64), o2=__shfl_xor(a2,OFF,64), o3=__shfl_xor(a3,OFF,64); \
    float o4=__shfl_xor(a4,OFF,64), o5=__shfl_xor(a5,OFF,64), o6=__shfl_xor(a6,OFF,64), o7=__shfl_xor(a7,OFF,64); \
    float o8=__shfl_xor(a8,OFF,64), o9=__shfl_xor(a9,OFF,64), oA=__shfl_xor(aA,OFF,64), oB=__shfl_xor(aB,OFF,64); \
    float oC=__shfl_xor(aC,OFF,64), oD=__shfl_xor(aD,OFF,64), oE=__shfl_xor(aE,OFF,64), oF=__shfl_xor(aF,OFF,64); \
    float M = fmaxf(m, mo); \
    float sS = __expf(m - M), sO = __expf(mo - M); \
    den = den*sS + dno*sO; \
    a0=a0*sS+o0*sO; a1=a1*sS+o1*sO; a2=a2*sS+o2*sO; a3=a3*sS+o3*sO; \
    a4=a4*sS+o4*sO; a5=a5*sS+o5*sO; a6=a6*sS+o6*sO; a7=a7*sS+o7*sO; \
    a8=a8*sS+o8*sO; a9=a9*sS+o9*sO; aA=aA*sS+oA*sO; aB=aB*sS+oB*sO; \
    aC=aC*sS+oC*sO; aD=aD*sS+oD*sO; aE=aE*sS+oE*sO; aF=aF*sS+oF*sO; \
    m = M; }

template<bool BF16OUT>
__global__ __launch_bounds__(256) void k_aggregate4(const unsigned char* __restrict__ hb8,
        const float* __restrict__ als, const float* __restrict__ ald,
        const float* __restrict__ ale, const float* __restrict__ alloop,
        const int* __restrict__ rs, const int2* __restrict__ sedge,
        const float* __restrict__ bias, void* __restrict__ outp){
    int n = blockIdx.x * 4 + (threadIdx.x >> 6);
    if (n >= N_) return;
    int lane = threadIdx.x & 63;
    int q  = lane >> 4;
    int sl = lane & 15;
    int col0 = sl * 16;
    int hd = sl >> 2;
    float aldn = ald[(size_t)n * 4 + hd];
    float alp  = alloop[hd];
    int i0 = rs[n], i1 = rs[n + 1];
    float m = -3.0e38f, den = 0.f;
    float a0=0.f,a1=0.f,a2=0.f,a3=0.f,a4=0.f,a5=0.f,a6=0.f,a7=0.f;
    float a8=0.f,a9=0.f,aA=0.f,aB=0.f,aC=0.f,aD=0.f,aE=0.f,aF=0.f;
    for (int i = i0 + q; i < i1; i += 4){
        int2 se = sedge[i];
        int s   = se.x;
        int eid = se.y;
        float alE = (eid < E_) ? ale[(size_t)eid * 4 + hd] : alp;
        float lg = als[(size_t)s * 4 + hd] + aldn + alE;
        lg = lrelu(lg, NEG_ATT);
        float mn = fmaxf(m, lg);
        float sc = __expf(m - mn);
        float p  = __expf(lg - mn);
        den = den * sc + p;
        uint4 g = *reinterpret_cast<const uint4*>(hb8 + (size_t)s * 256 + col0);
        float t0, t1, t2, t3;
        dec4(g.x, t0, t1, t2, t3);
        a0 = a0*sc + p*t0;  a1 = a1*sc + p*t1;  a2 = a2*sc + p*t2;  a3 = a3*sc + p*t3;
        dec4(g.y, t0, t1, t2, t3);
        a4 = a4*sc + p*t0;  a5 = a5*sc + p*t1;  a6 = a6*sc + p*t2;  a7 = a7*sc + p*t3;
        dec4(g.z, t0, t1, t2, t3);
        a8 = a8*sc + p*t0;  a9 = a9*sc + p*t1;  aA = aA*sc + p*t2;  aB = aB*sc + p*t3;
        dec4(g.w, t0, t1, t2, t3);
        aC = aC*sc + p*t0;  aD = aD*sc + p*t1;  aE = aE*sc + p*t2;  aF = aF*sc + p*t3;
        m = mn;
    }
    MERGE4(16)
    MERGE4(32)
    float inv = 1.f / den;
    float v0, v1, v2, v3;
    if      (q == 0){ v0 = a0; v1 = a1; v2 = a2; v3 = a3; }
    else if (q == 1){ v0 = a4; v1 = a5; v2 = a6; v3 = a7; }
    else if (q == 2){ v0 = a8; v1 = a9; v2 = aA; v3 = aB; }
    else            { v0 = aC; v1 = aD; v2 = aE; v3 = aF; }
    int wc = col0 + q * 4;
    float4 b4 = *reinterpret_cast<const float4*>(bias + wc);
    float r0 = lrelu(v0 * inv + b4.x, NEG_OUT);
    float r1 = lrelu(v1 * inv + b4.y, NEG_OUT);
    float r2 = lrelu(v2 * inv + b4.z, NEG_OUT);
    float r3 = lrelu(v3 * inv + b4.w, NEG_OUT);
    if (BF16OUT){
        ushort4 pk;
        pk.x = bf16rne(r0); pk.y = bf16rne(r1); pk.z = bf16rne(r2); pk.w = bf16rne(r3);
        *reinterpret_cast<ushort4*>((unsigned short*)outp + (size_t)n * 256 + wc) = pk;
    } else {
        *reinterpret_cast<float4*>((float*)outp + (size_t)n * 256 + wc) =
            make_float4(r0, r1, r2, r3);
    }
}

// ---------- edge_index passthrough (fp32, bit-exact) ----------
__global__ void k_edge_store(const int* __restrict__ ei, float* __restrict__ out){
    int j = blockIdx.x * blockDim.x + threadIdx.x;     // 2E
    if (j >= (int)OUT1) return;
    out[j] = (float)ei[j];
}

extern "C" void kernel_launch(void* const* d_in, const int* in_sizes, int n_in,
                              void* d_out, int out_size, void* d_ws, size_t ws_size,
                              hipStream_t stream){
    const float* x    = (const float*)d_in[0];
    const int*   ei   = (const int*)d_in[1];
    const float* ea   = (const float*)d_in[2];
    const float* bn1g = (const float*)d_in[3];
    const float* bn1b = (const float*)d_in[4];
    const float* W1   = (const float*)d_in[5];
    const float* We1  = (const float*)d_in[6];
    const float* as1  = (const float*)d_in[7];
    const float* ad1  = (const float*)d_in[8];
    const float* ae1  = (const float*)d_in[9];
    const float* b1   = (const float*)d_in[10];
    const float* bn2g = (const float*)d_in[11];
    const float* bn2b = (const float*)d_in[12];
    const float* W2   = (const float*)d_in[13];
    const float* We2  = (const float*)d_in[14];
    const float* as2  = (const float*)d_in[15];
    const float* ad2  = (const float*)d_in[16];
    const float* ae2  = (const float*)d_in[17];
    const float* b2   = (const float*)d_in[18];
    float* out = (float*)d_out;

    bool ok = (n_in >= 19)
           && (in_sizes[0] == N_ * FIN)
           && (in_sizes[1] == 2 * E_)
           && (in_sizes[2] == E_ * 16)
           && (out_size == (int)(OUT0 + OUT1));
    if (!ok){ k_sentinel<<<1,1,0,stream>>>(out, 7777.f); return; }

    char* w = (char*)d_ws;
    size_t off = 0;
    auto alloc = [&](size_t bytes) -> void* {
        off = (off + 255) & ~(size_t)255;
        void* p = w + off;
        off += bytes;
        return p;
    };
    float* stats  = (float*)alloc(512 * 4);                      // sum[256], sumsq[256]
    float* bnsc   = (float*)alloc(256 * 4);                      // BN scale
    float* bnsh   = (float*)alloc(256 * 4);                      // BN shift
    float* asum   = (float*)alloc(16 * 4);
    float* apart  = (float*)alloc((size_t)ATTR_NBLK * 16 * 4);   // 64KB
    float* Vbuf   = (float*)alloc(64 * 4);
    float* alloop = (float*)alloc(4 * 4);
    float* als    = (float*)alloc((size_t)N_ * 4 * 4);
    float* ald    = (float*)alloc((size_t)N_ * 4 * 4);
    float* ale    = (float*)alloc((size_t)E_ * 4 * 4);           // 12.8MB
    int*   rs     = (int*)alloc((size_t)(N_ + 1) * 4);
    int*   cc     = (int*)alloc((size_t)N_ * 2 * 4);             // counts[N] + cursor[N], contiguous
    int*   bsum   = (int*)alloc((size_t)SCAN_NBLK * 4);
    int*   boff   = (int*)alloc((size_t)SCAN_NBLK * 4);
    int2*  sedge  = (int2*)alloc((size_t)E2_ * 8);               // 6.8MB packed (src,eid)
    unsigned short* WT1 = (unsigned short*)alloc((size_t)256 * FIN * 2);  // 64KB
    unsigned short* WT2 = (unsigned short*)alloc((size_t)256 * FH * 2);   // 128KB
    unsigned short* hbuf = (unsigned short*)alloc((size_t)N_ * 256 * 2);  // 25.6MB bf16
    unsigned char*  hbuf8 = (unsigned char*)alloc((size_t)N_ * 256);      // 12.8MB fp8
    unsigned short* bufB = (unsigned short*)alloc((size_t)N_ * 256 * 2);  // 25.6MB bf16
    if (off > ws_size){ k_sentinel<<<1,1,0,stream>>>(out, 5555.f); return; }

    int* counts = cc;
    int* cursor = cc + N_;
    float* ssum = stats;
    float* ssq  = stats + 256;
    const int GX = cdiv(N_, 64);    // 782

    // ---- CSR build (shared by both layers) ----
    k_zero32<<<cdiv(2*N_,256),256,0,stream>>>((unsigned*)cc, 2 * N_);
    k_count<<<cdiv(E2_,256),256,0,stream>>>(ei, counts);
    k_scan_local<<<SCAN_NBLK,256,0,stream>>>(counts, rs, bsum);
    k_scan_block<<<1,256,0,stream>>>(bsum, boff, rs);
    k_scan_add<<<SCAN_NBLK,256,0,stream>>>(rs, boff);
    k_scatter<<<cdiv(E2_,256),256,0,stream>>>(ei, rs, cursor, sedge);

    // ---- shared precompute ----
    k_attr_sum<<<ATTR_NBLK,256,0,stream>>>(ea, apart);
    k_attr_fin<<<1,256,0,stream>>>(apart, asum);
    k_w2t<<<FIN,256,0,stream>>>(W1, WT1, FIN);
    k_w2t<<<FH,256,0,stream>>>(W2, WT2, FH);

    // ---- BN1 stats -> affine params ----
    k_zero32<<<2,256,0,stream>>>((unsigned*)stats, 512);
    k_bn_stats<<<256,256,0,stream>>>(x, FIN, ssum, ssq);
    k_bnp<<<1,FIN,0,stream>>>(ssum, ssq, bn1g, bn1b, bnsc, bnsh, FIN);

    // ---- GAT layer 1 (BN fused into GEMM A-load) ----
    k_gemm_bn<true><<<dim3(GX,4),256,0,stream>>>(x, WT1, bnsc, bnsh, hbuf, hbuf8, N_, FIN);
    k_al<<<cdiv(N_,4),256,0,stream>>>(hbuf, as1, ad1, als, ald);
    k_prep<<<1,64,0,stream>>>(We1, ae1, asum, Vbuf, alloop);
    k_al_edge<<<cdiv(E_*4,256),256,0,stream>>>(ea, Vbuf, ale);
    k_aggregate4<true><<<cdiv(N_,4),256,0,stream>>>(hbuf8, als, ald, ale, alloop,
                                                    rs, sedge, b1, bufB);

    // ---- BN2 stats -> affine params ----
    k_zero32<<<2,256,0,stream>>>((unsigned*)stats, 512);
    k_bn_stats_b16<<<256,256,0,stream>>>(bufB, FH, ssum, ssq);
    k_bnp<<<1,FH,0,stream>>>(ssum, ssq, bn2g, bn2b, bnsc, bnsh, FH);

    // ---- GAT layer 2 (BN fused into GEMM A-load) ----
    k_gemm_bn<false><<<dim3(GX,4),256,0,stream>>>(bufB, WT2, bnsc, bnsh, hbuf, hbuf8, N_, FH);
    k_al<<<cdiv(N_,4),256,0,stream>>>(hbuf, as2, ad2, als, ald);
    k_prep<<<1,64,0,stream>>>(We2, ae2, asum, Vbuf, alloop);
    k_al_edge<<<cdiv(E_*4,256),256,0,stream>>>(ea, Vbuf, ale);
    k_aggregate4<false><<<cdiv(N_,4),256,0,stream>>>(hbuf8, als, ald, ale, alloop,
                                                     rs, sedge, b2, out);

    // ---- edge_index passthrough ----
    k_edge_store<<<cdiv((int)OUT1,256),256,0,stream>>>(ei, out + OUT0);
}